// Round 1
// baseline (500.951 us; speedup 1.0000x reference)
//
#include <hip/hip_runtime.h>
#include <math.h>

typedef unsigned long long u64;
typedef unsigned int u32;

static constexpr int S    = 771;   // NB_LABELS*MAX_DEPTH + EXTRA
static constexpr int Tn   = 128;
static constexpr int Bn   = 32;
static constexpr int BOSs = 0;
static constexpr int EOSs = 1;

static constexpr int JPAD  = 832;          // 13 * 64 state pad
static constexpr int JB    = 13;           // state-blocks per batch (grid.x)
static constexpr int NW    = 4;            // waves per block
static constexpr int KK    = 13;           // uint4 (16 i8) per lane: 208 i8 = one K-quarter
static constexpr int NDATA = JB * 16;      // 208 tagged data words per generation
static constexpr int NMAX  = JB * NW;      // 52 tagged per-wave max words per generation
static constexpr int XSTR  = 272;          // u64 stride per (parity,batch) slot (>=260)
static constexpr int EBLK  = NW * KK * 64 * 16;   // 53248 B per jblk
static constexpr int ETOT  = JB * EBLK;           // 692224 B
static constexpr float CB  = 8.0f;         // normalizer headroom (drift bound)
static constexpr float C0V = 4.5f;         // fixed normalizer for t=0 publish

__device__ __forceinline__ float wave_max_bfly(float v) {   // result in ALL lanes
    #pragma unroll
    for (int off = 32; off > 0; off >>= 1) v = fmaxf(v, __shfl_xor(v, off));
    return v;
}
__device__ __forceinline__ float wave_sum_f(float v) {      // full sum (bpermute wraps)
    #pragma unroll
    for (int off = 32; off > 0; off >>= 1) v += __shfl_down(v, off);
    return v;
}

__device__ __forceinline__ u64 ald64(const u64* p) {
    return __hip_atomic_load((u64*)p, __ATOMIC_RELAXED, __HIP_MEMORY_SCOPE_AGENT);
}
__device__ __forceinline__ void ast64(u64* p, u64 v) {
    __hip_atomic_store(p, v, __ATOMIC_RELAXED, __HIP_MEMORY_SCOPE_AGENT);
}
__device__ __forceinline__ u64 pack(unsigned tag, unsigned payload) {
    return ((u64)tag << 32) | (u64)payload;
}

// i8 x i8 + i32 dot (both operands in [0,127], so signed == unsigned)
#if __has_builtin(__builtin_amdgcn_sdot4)
__device__ __forceinline__ int dot4i(unsigned a, unsigned b, int c) {
    return __builtin_amdgcn_sdot4((int)a, (int)b, c, false);
}
#else
__device__ __forceinline__ int dot4i(unsigned a, unsigned b, int c) {
    c += (int)(a & 0xff)         * (int)(b & 0xff);
    c += (int)((a >> 8) & 0xff)  * (int)((b >> 8) & 0xff);
    c += (int)((a >> 16) & 0xff) * (int)((b >> 16) & 0xff);
    c += (int)((a >> 24) & 0xff) * (int)((b >> 24) & 0xff);
    return c;
}
#endif

// ---------------------------------------------------------------------------
// Prep (r11 layout): i8 exp-transition table swizzled for PER-WAVE full-K dots.
// eswz[jblk][w][kk][lane][16] = round(115*exp(trans[i][j])) in [0,127],
//   i = (lane>>4)*208 + kk*16 + e   (inner state, lane's K-quarter)
//   j = jblk*64 + w*16 + (lane&15)  (output state owned by wave w)
// Also eteos = exp(trans[:,EOS]) f32 column (unchanged).
// ---------------------------------------------------------------------------
extern "C" __global__ void build_tabs(const float* __restrict__ trans,
                                      unsigned char* __restrict__ eswz,
                                      float* __restrict__ eteos) {
    int idx = blockIdx.x * blockDim.x + threadIdx.x;
    if (idx < JPAD)
        eteos[idx] = (idx < S) ? __expf(trans[idx * S + EOSs]) : 0.f;
    if (idx >= ETOT) return;
    int e = idx & 15;
    int r = idx >> 4;
    int lane = r & 63;  r >>= 6;
    int kk = r % 13;
    int h  = r / 13;
    int w  = h & 3, jblk = h >> 2;
    int i = (lane >> 4) * 208 + kk * 16 + e;
    int j = jblk * 64 + w * 16 + (lane & 15);
    float v = 0.f;
    if (i < S && j < S) v = 115.f * __expf(trans[i * S + j]);
    int q8 = (int)(v + 0.5f);
    if (q8 > 127) q8 = 127;
    eswz[idx] = (unsigned char)q8;
}

// per-WAVE publish: wave w owns output states [16w,16w+16) of its chunk.
// Data: 4 u64 words (word 16*jblk+4w+k = states 4k..4k+3, p8-packed), one
// predicated store by lanes 0..3. Max: per-wave af max, word NDATA+4*jblk+w.
__device__ __forceinline__ void publish(u64* Wp, int jblk, int w, unsigned tag,
                                        float af, float C, int lane) {
    float xf = fminf(127.f, 127.f * __expf(af - C));   // -inf/-1e9 -> 0
    int xi = (int)(xf + 0.5f);
    int b0 = __shfl(xi, (4 * lane) & 63);              // sources: lanes 0..15 (q=0)
    int b1 = __shfl(xi, (4 * lane + 1) & 63);
    int b2 = __shfl(xi, (4 * lane + 2) & 63);
    int b3 = __shfl(xi, (4 * lane + 3) & 63);
    unsigned payload = (unsigned)b0 | ((unsigned)b1 << 8)
                     | ((unsigned)b2 << 16) | ((unsigned)b3 << 24);
    float mc = wave_max_bfly(af);                      // dup across quarters: same max
    if (lane < 4)  ast64(Wp + jblk * 16 + 4 * w + lane, pack(tag, payload));
    if (lane == 4) ast64(Wp + NDATA + jblk * NW + w,    pack(tag, __float_as_uint(mc)));
}

// ---------------------------------------------------------------------------
// Forward algorithm, r11: BARRIER-FREE per-wave pipelines.
// Each wave computes FULL-K dots for its own 16 output states: lane =
// (quarter = lane>>4, out = lane&15); quarters combined by 2 in-wave
// shfl_xor adds. E slice lives in 13 uint4 REGISTERS (loop-invariant) -> the
// 53KB/step LDS E re-read, the per-step __syncthreads, the LDS partial
// combine and the wave0-serial epilogue are all gone from the 127-step
// critical path. Cost: each wave polls all 260 words (4x traffic), but each
// consumer lane waits on exactly ONE publisher wave (its 4 data words + max
// word are two back-to-back stores -> coherent arrival).
// Sync safety (word granularity): wave publishes gen t only after consuming
// ALL 260 words of gen t-1; the 260 words cover every (block,wave)
// publisher, so gen t+2 overwrites only after every wave consumed gen t.
// Numerics identical to r10 (same E quant, p8, Cnew=max+CB 1-step lag, C0V).
// ---------------------------------------------------------------------------
extern "C" __global__ __launch_bounds__(256, 2)
void crf_fwd(const float* __restrict__ em, const float* __restrict__ mask,
             const float* __restrict__ trans, const int* __restrict__ tags,
             const unsigned char* __restrict__ eswz,
             const float* __restrict__ eteos,
             u64* __restrict__ xb, float* __restrict__ out) {
    const int jblk = blockIdx.x, b = blockIdx.y;
    const int tid = threadIdx.x, lane = tid & 63, w = tid >> 6;
    const int q  = lane >> 4;                 // K-quarter of this lane
    const int jl = lane & 15;                 // output index within wave
    const int j  = jblk * 64 + w * 16 + jl;   // global output state

    __shared__ u32 strip[NW][NDATA];          // per-wave p8 vector, i-order (832 i8)
    __shared__ float cshare;
    __shared__ float redv[NW], redm[NW], redl[NW];

    const float KLOG  = __logf(115.f * 127.f);
    const float KL127 = __logf(127.f);

    // ---- t=0: publish first (unblocks everyone), then load E into regs ----
    float af = -INFINITY, Cuse = C0V;
    if (j < S) af = trans[BOSs * S + j] + em[((size_t)b * Tn + 0) * S + j];
    publish(xb + ((size_t)0 * Bn + b) * XSTR, jblk, w, 0u, af, C0V, lane);

    uint4 ereg[KK];                           // 208 i8 of E: rows=lane's quarter, col=j
    {
        const uint4* src = (const uint4*)eswz + ((size_t)(jblk * NW + w) * KK) * 64 + lane;
        #pragma unroll
        for (int kk = 0; kk < KK; ++kk) ereg[kk] = src[kk * 64];
    }

    const bool act = (lane < 52);             // lanes 0..51 poll 4 data + 1 max word

    // ---- 127 sequential steps, zero barriers ----
    for (int t = 1; t < Tn; ++t) {
        const u64* R  = xb + ((size_t)((t - 1) & 1) * Bn + b) * XSTR;
        u64*       Wp = xb + ((size_t)((t    ) & 1) * Bn + b) * XSTR;

        // epilogue operands independent of alpha: issue before the poll
        float emv = 0.f;
        if (j < S) emv = em[((size_t)b * Tn + t) * S + j];
        float mval = mask[b * Tn + t];

        // ---- poll: lane L waits on publisher (block L>>2, wave L&3) ----
        const unsigned tg = (unsigned)(t - 1);
        const u64* pd = R + 4 * lane;         // words 4L..4L+3 (one publisher store)
        const u64* pm = R + NDATA + lane;     // same publisher's max word
        u64 d0 = 0, d1 = 0, d2 = 0, d3 = 0, qm = 0;
        bool o0 = !act, o1 = !act, o2 = !act, o3 = !act, om = !act;
        do {
            if (!o0) { d0 = ald64(pd + 0); o0 = ((unsigned)(d0 >> 32) == tg); }
            if (!o1) { d1 = ald64(pd + 1); o1 = ((unsigned)(d1 >> 32) == tg); }
            if (!o2) { d2 = ald64(pd + 2); o2 = ((unsigned)(d2 >> 32) == tg); }
            if (!o3) { d3 = ald64(pd + 3); o3 = ((unsigned)(d3 >> 32) == tg); }
            if (!om) { qm = ald64(pm);     om = ((unsigned)(qm >> 32) == tg); }
        } while (__any((!o0) | (!o1) | (!o2) | (!o3) | (!om)));

        // ---- own strip (same-wave DS write->read: in-order pipe, no barrier)
        if (act) {
            u64 w01 = ((u64)(u32)d1 << 32) | (u64)(u32)d0;
            u64 w23 = ((u64)(u32)d3 << 32) | (u64)(u32)d2;
            *(u64*)&strip[w][4 * lane]     = w01;
            *(u64*)&strip[w][4 * lane + 2] = w23;
        }

        // next normalizer from the 52 per-wave maxes (redundant per wave)
        float mv = act ? __uint_as_float((u32)qm) : -INFINITY;
        float Cnew = wave_max_bfly(mv) + CB;

        // ---- full-K dot: 13 in-reg E uint4 x 13 strip uint4 (broadcast) ----
        int a0 = 0, a1 = 0, a2 = 0, a3 = 0;
        const uint4* P4 = (const uint4*)&strip[w][0] + q * KK;
        #pragma unroll
        for (int kk = 0; kk < KK; ++kk) {
            const uint4 pv = P4[kk];
            a0 = dot4i(ereg[kk].x, pv.x, a0);
            a1 = dot4i(ereg[kk].y, pv.y, a1);
            a2 = dot4i(ereg[kk].z, pv.z, a2);
            a3 = dot4i(ereg[kk].w, pv.w, a3);
        }
        int s4 = (a0 + a1) + (a2 + a3);
        s4 += __shfl_xor(s4, 16);             // combine the 4 K-quarters in-wave
        s4 += __shfl_xor(s4, 32);

        // ---- epilogue (all waves, no barrier): log, select, publish gen t
        float nv = Cuse - KLOG + __logf((float)s4) + emv;   // log(0) = -inf
        af = (mval > 0.f) ? nv : af;
        publish(Wp, jblk, w, (unsigned)t, af, Cnew, lane);
        Cuse = Cnew;
    }

    if (w == 0 && lane == 0) cshare = Cuse;   // C used for the gen-127 publish

    // ---- tail (blocks jblk==0 only): log_Z + gold score + output ----
    if (jblk == 0) {
        const u64* R = xb + ((size_t)((Tn - 1) & 1) * Bn + b) * XSTR;
        const unsigned tg = (unsigned)(Tn - 1);
        const bool tact = (tid < NDATA);
        u64 qd = 0;
        bool ok = !tact;
        while (true) {
            if (!ok) { qd = ald64(R + tid); ok = ((unsigned)(qd >> 32) == tg); }
            if (__syncthreads_and(ok)) break;
        }
        float lsum = 0.f;
        if (tact) {
            unsigned pv = (unsigned)qd;
            int base = 4 * tid;               // p8 index j = 4*word + e
            lsum = (float)(pv & 0xff)         * eteos[base]
                 + (float)((pv >> 8)  & 0xff) * eteos[base + 1]
                 + (float)((pv >> 16) & 0xff) * eteos[base + 2]
                 + (float)((pv >> 24) & 0xff) * eteos[base + 3];
        }
        // gold-path score: thread tid<128 handles position tid
        float mk = 0.f, val = 0.f;
        if (tid < Tn) {
            mk = mask[b * Tn + tid];
            if (tid > 0) {
                int cur  = tags[b * Tn + tid];
                int prev = tags[b * Tn + tid - 1];
                val = (em[((size_t)b * Tn + tid) * S + cur]
                       + trans[prev * S + cur]) * mk;
            }
        }
        lsum = wave_sum_f(lsum);
        float vs = wave_sum_f(val);
        float ms = wave_sum_f(mk);
        if (lane == 0) { redv[w] = vs; redm[w] = ms; }
        if (lane == 1) redl[w] = lsum;
        __syncthreads();
        if (tid == 0) {
            float tot  = redl[0] + redl[1] + redl[2] + redl[3];
            float logz = cshare - KL127 + __logf(tot);
            float msum = redm[0] + redm[1] + redm[2] + redm[3];
            int last   = (int)(msum + 0.5f) - 1;
            int first  = tags[b * Tn];
            int lastt  = tags[b * Tn + last];
            float score = redv[0] + redv[1] + redv[2] + redv[3]
                        + trans[BOSs * S + first]
                        + em[((size_t)b * Tn) * S + first]
                        + trans[lastt * S + EOSs];
            atomicAdd(out, -(score - logz));
        }
    }
}

extern "C" void kernel_launch(void* const* d_in, const int* in_sizes, int n_in,
                              void* d_out, int out_size, void* d_ws, size_t ws_size,
                              hipStream_t stream) {
    const float* em    = (const float*)d_in[0];
    const int*   tags  = (const int*)d_in[1];
    const float* mask  = (const float*)d_in[2];
    const float* trans = (const float*)d_in[3];
    float* out = (float*)d_out;

    char* ws = (char*)d_ws;
    size_t off = 0;
    unsigned char* eswz = (unsigned char*)(ws + off);
    off += (size_t)ETOT;
    off = (off + 255) & ~(size_t)255;
    float* eteos = (float*)(ws + off); off += JPAD * sizeof(float);
    off = (off + 255) & ~(size_t)255;
    u64* xb = (u64*)(ws + off);        off += (size_t)2 * Bn * XSTR * sizeof(u64);

    // ws re-poisoned 0xAA pre-launch: stale tags (0xAAAAAAAA) never match t<128
    (void)hipMemsetAsync(out, 0, sizeof(float), stream);

    build_tabs<<<(ETOT + 255) / 256, 256, 0, stream>>>(trans, eswz, eteos);
    crf_fwd<<<dim3(JB, Bn), 256, 0, stream>>>(em, mask, trans, tags, eswz,
                                              eteos, xb, out);
}

// Round 2
// 360.654 us; speedup vs baseline: 1.3890x; 1.3890x over previous
//
#include <hip/hip_runtime.h>
#include <math.h>

typedef unsigned long long u64;
typedef unsigned int u32;

static constexpr int S    = 771;   // NB_LABELS*MAX_DEPTH + EXTRA
static constexpr int Tn   = 128;
static constexpr int Bn   = 32;
static constexpr int BOSs = 0;
static constexpr int EOSs = 1;

// r12 geometry: 7 blocks x 128 rows per batch -> 224 blocks total = 1/CU.
static constexpr int JB    = 7;            // state-blocks per batch (grid.x)
static constexpr int ROWS  = 128;          // output rows per block
static constexpr int JPAD  = JB * ROWS;    // 896 padded states
static constexpr int NW    = 4;            // waves per block (K-quarters)
static constexpr int KQ    = JPAD / NW;    // 224 i8 inner slice per wave
static constexpr int KW    = KQ / 4;       // 56 u32 words per quarter
static constexpr int KK    = KQ / 16;      // 14 uint4 per row-quarter
static constexpr int NDATA = JPAD / 4;     // 224 tagged data words per gen
static constexpr int NMAX  = JB * NW;      // 28 tagged per-wave max words
static constexpr int XSTR  = 256;          // u64 stride per (parity,batch)
static constexpr int EBLK  = NW * KK * 2 * 64 * 16;  // 114688 B per jblk
static constexpr int ETOT  = JB * EBLK;              // 802816 B
static constexpr float CB  = 8.0f;         // normalizer headroom (drift bound)
static constexpr float C0V = 4.5f;         // fixed normalizer for t=0 publish

__device__ __forceinline__ float wave_max_bfly(float v) {   // result in ALL lanes
    #pragma unroll
    for (int off = 32; off > 0; off >>= 1) v = fmaxf(v, __shfl_xor(v, off));
    return v;
}
__device__ __forceinline__ float wave_sum_f(float v) {
    #pragma unroll
    for (int off = 32; off > 0; off >>= 1) v += __shfl_down(v, off);
    return v;
}

__device__ __forceinline__ u64 ald64(const u64* p) {
    return __hip_atomic_load((u64*)p, __ATOMIC_RELAXED, __HIP_MEMORY_SCOPE_AGENT);
}
__device__ __forceinline__ void ast64(u64* p, u64 v) {
    __hip_atomic_store(p, v, __ATOMIC_RELAXED, __HIP_MEMORY_SCOPE_AGENT);
}
__device__ __forceinline__ u64 pack(unsigned tag, unsigned payload) {
    return ((u64)tag << 32) | (u64)payload;
}

// i8 x i8 + i32 dot (both operands in [0,127], so signed == unsigned)
#if __has_builtin(__builtin_amdgcn_sdot4)
__device__ __forceinline__ int dot4i(unsigned a, unsigned b, int c) {
    return __builtin_amdgcn_sdot4((int)a, (int)b, c, false);
}
#else
__device__ __forceinline__ int dot4i(unsigned a, unsigned b, int c) {
    c += (int)(a & 0xff)         * (int)(b & 0xff);
    c += (int)((a >> 8) & 0xff)  * (int)((b >> 8) & 0xff);
    c += (int)((a >> 16) & 0xff) * (int)((b >> 16) & 0xff);
    c += (int)((a >> 24) & 0xff) * (int)((b >> 24) & 0xff);
    return c;
}
#endif

// ---------------------------------------------------------------------------
// Prep (r12 layout): i8 exp-transition table for REGISTER-resident E.
// Linear u128 index (((jb*4 + w)*14 + kk)*2 + rr)*64 + lane holds 16 i8:
//   i = w*224 + kk*16 + e   (inner state: wave w's K-quarter)
//   j = jb*128 + rr*64 + lane  (output row; lane computes rows rr=0,1)
// value = round(115*exp(trans[i][j])) in [0,127].
// ---------------------------------------------------------------------------
extern "C" __global__ void build_tabs(const float* __restrict__ trans,
                                      unsigned char* __restrict__ eswz,
                                      float* __restrict__ eteos) {
    int idx = blockIdx.x * blockDim.x + threadIdx.x;
    if (idx < JPAD)
        eteos[idx] = (idx < S) ? __expf(trans[idx * S + EOSs]) : 0.f;
    if (idx >= ETOT) return;
    int e = idx & 15;
    int u = idx >> 4;
    int lane = u & 63;  u >>= 6;
    int rr = u & 1;     u >>= 1;
    int kk = u % KK;
    int h  = u / KK;
    int w  = h & 3, jb = h >> 2;
    int i = w * KQ + kk * 16 + e;
    int j = jb * ROWS + rr * 64 + lane;
    float v = 0.f;
    if (i < S && j < S) v = 115.f * __expf(trans[i * S + j]);
    int q8 = (int)(v + 0.5f);
    if (q8 > 127) q8 = 127;
    eswz[idx] = (unsigned char)q8;
}

// per-wave publish: wave w owns rows [32w, 32w+32) of its block (af in lanes
// 0..31). 8 data u64 (word 32jb+8w+k = rows 4k..4k+3 p8-packed) + 1 max u64
// (word NDATA + 4jb + w = wave max). Tag stream IS the sync.
__device__ __forceinline__ void publishW(u64* Wp, int jb, int w, unsigned tag,
                                         float af, float C, int lane) {
    float xf = fminf(127.f, 127.f * __expf(af - C));   // -inf/-1e9 -> 0
    int xi = (int)(xf + 0.5f);
    int b0 = __shfl(xi, (4 * lane) & 63);
    int b1 = __shfl(xi, (4 * lane + 1) & 63);
    int b2 = __shfl(xi, (4 * lane + 2) & 63);
    int b3 = __shfl(xi, (4 * lane + 3) & 63);
    unsigned payload = (unsigned)b0 | ((unsigned)b1 << 8)
                     | ((unsigned)b2 << 16) | ((unsigned)b3 << 24);
    float mc = wave_max_bfly(af);                      // lanes>=32 are -inf
    if (lane < 8)  ast64(Wp + 32 * jb + 8 * w + lane, pack(tag, payload));
    if (lane == 8) ast64(Wp + NDATA + 4 * jb + w,     pack(tag, __float_as_uint(mc)));
}

// ---------------------------------------------------------------------------
// Forward algorithm, r12.
//  - 7x128 tile: 224 blocks -> 1 block/CU (no SIMD/LDS sharing; r10's 416
//    blocks put 2 blocks on 160 CUs and the all-to-all chain runs at the
//    SLOWEST block's speed).
//  - r10 dataflow kept: wave w = K-quarter w for all 128 rows; its 56 data
//    words come from only 2-3 publisher blocks, so publisher skew stalls one
//    wave, not the block; ONE barrier combines quarters.
//  - E tile in REGISTERS: 2 rows x 14 uint4 = 112 VGPR/lane, pinned by an
//    opaque asm so the compiler cannot sink the loads into the t-loop
//    (r11 failure mode: VGPR_Count=56 proved E was reloaded every step).
//  - Pipelined poll: check the load issued last iteration while the next is
//    in flight -> detection ~0.75 lambda instead of ~1.5 lambda.
//  - Distributed epilogue: each wave combines + publishes its own 32 rows;
//    the wave0-serial 64-row exp/log/pack tail is gone.
// Sync safety: per-word tags; the 4 waves' polls jointly cover ALL 224+28
// words of gen t-1 before the barrier preceding the gen-t publish, so the
// parity-slot overwrite transitivity (r8 argument) holds unchanged.
// Numerics identical to r10 (same E quant, p8, Cnew = max+CB 1-step lag).
// ---------------------------------------------------------------------------
extern "C" __global__ __launch_bounds__(256, 1)
void crf_fwd(const float* __restrict__ em, const float* __restrict__ mask,
             const float* __restrict__ trans, const int* __restrict__ tags,
             const unsigned char* __restrict__ eswz,
             const float* __restrict__ eteos,
             u64* __restrict__ xb, float* __restrict__ out) {
    const int jb = blockIdx.x, b = blockIdx.y;
    const int tid = threadIdx.x, lane = tid & 63, w = tid >> 6;

    __shared__ __align__(16) u32 strip[NW * KW];      // per-wave quarter p8
    __shared__ int   part[2][NW][ROWS];
    __shared__ float mred[2][NW];
    __shared__ float cshare;
    __shared__ float redv[NW], redm[NW], redl[NW];

    const float KLOG  = __logf(115.f * 127.f);
    const float KL127 = __logf(127.f);

    // epilogue rows of this wave: lane l<32 owns row jb*128 + 32w + l
    const int jrow = jb * ROWS + 32 * w + lane;

    // ---- t=0: publish first (unblocks everyone), then load E into regs ----
    float af = -INFINITY, Cuse = C0V;
    if (lane < 32 && jrow < S)
        af = trans[BOSs * S + jrow] + em[((size_t)b * Tn + 0) * S + jrow];
    publishW(xb + ((size_t)0 * Bn + b) * XSTR, jb, w, 0u, af, C0V, lane);

    uint4 e0[KK], e1[KK];                  // E: rows (lane, lane+64), quarter w
    {
        const uint4* src = (const uint4*)eswz
                         + ((size_t)(jb * NW + w) * KK * 2) * 64 + lane;
        #pragma unroll
        for (int kk = 0; kk < KK; ++kk) {
            e0[kk] = src[(kk * 2 + 0) * 64];
            e1[kk] = src[(kk * 2 + 1) * 64];
        }
    }
    // opaque pin: forces VGPR residency, forbids sinking loads into the loop
    #pragma unroll
    for (int kk = 0; kk < KK; ++kk) {
        asm volatile("" : "+v"(e0[kk].x), "+v"(e0[kk].y), "+v"(e0[kk].z), "+v"(e0[kk].w));
        asm volatile("" : "+v"(e1[kk].x), "+v"(e1[kk].y), "+v"(e1[kk].z), "+v"(e1[kk].w));
    }

    const bool actd = (lane < KW);                   // 56 data-poll lanes
    const bool actm = (lane >= KW) && (lane < KW + 7); // 7 max-poll lanes

    // ---- 127 sequential steps, one barrier each ----
    for (int t = 1; t < Tn; ++t) {
        const u64* R  = xb + ((size_t)((t - 1) & 1) * Bn + b) * XSTR;
        u64*       Wp = xb + ((size_t)((t    ) & 1) * Bn + b) * XSTR;

        // epilogue operands independent of alpha: issue before the poll
        float emv = 0.f;
        if (lane < 32 && jrow < S) emv = em[((size_t)b * Tn + t) * S + jrow];
        float mval = mask[b * Tn + t];

        // ---- pipelined poll: wave w waits only on its quarter's publishers
        const unsigned tg = (unsigned)(t - 1);
        const u64* pd = R + KW * w + lane;               // data word (lane<56)
        const u64* pm = R + NDATA + 7 * w + (lane - KW); // max word (7 lanes)
        u64 dc = 0, dn = 0, mc = 0, mn = 0;
        bool okd = !actd, okm = !actm;
        if (actd) { dc = ald64(pd); dn = ald64(pd); }
        if (actm) { mc = ald64(pm); mn = ald64(pm); }
        while (true) {
            if (!okd) { if ((u32)(dc >> 32) == tg) okd = true; else dc = dn; }
            if (!okm) { if ((u32)(mc >> 32) == tg) okm = true; else mc = mn; }
            if (!__any((!okd) | (!okm))) break;
            if (!okd) dn = ald64(pd);
            if (!okm) mn = ald64(pm);
        }

        // ---- own strip (same-wave DS write->read: in-order, no barrier) ----
        if (actd) strip[w * KW + lane] = (u32)dc;

        // per-wave partial of next normalizer (full max after the barrier)
        float pmv = actm ? __uint_as_float((u32)mc) : -INFINITY;
        float wmax = wave_max_bfly(pmv);
        if (lane == 0) mred[t & 1][w] = wmax;

        // ---- dot: in-register E (2 rows) x quarter strip (b128 broadcast) --
        int a0 = 0, a1 = 0;
        const uint4* P4 = (const uint4*)(strip + w * KW);
        #pragma unroll
        for (int kk = 0; kk < KK; ++kk) {
            const uint4 pv = P4[kk];
            a0 = dot4i(e0[kk].x, pv.x, a0);
            a0 = dot4i(e0[kk].y, pv.y, a0);
            a0 = dot4i(e0[kk].z, pv.z, a0);
            a0 = dot4i(e0[kk].w, pv.w, a0);
            a1 = dot4i(e1[kk].x, pv.x, a1);
            a1 = dot4i(e1[kk].y, pv.y, a1);
            a1 = dot4i(e1[kk].z, pv.z, a1);
            a1 = dot4i(e1[kk].w, pv.w, a1);
        }
        part[t & 1][w][lane]      = a0;
        part[t & 1][w][64 + lane] = a1;
        __syncthreads();   // the ONLY per-step barrier

        // ---- distributed epilogue: wave w finishes rows 32w..32w+31 ----
        const int p_ = t & 1;
        const int Rr = 32 * w + (lane & 31);
        int s4 = part[p_][0][Rr] + part[p_][1][Rr]
               + part[p_][2][Rr] + part[p_][3][Rr];
        float Cnew = fmaxf(fmaxf(mred[p_][0], mred[p_][1]),
                           fmaxf(mred[p_][2], mred[p_][3])) + CB;
        float nv = Cuse - KLOG + __logf((float)s4) + emv;  // log(0) = -inf
        if (lane < 32) af = (mval > 0.f) ? nv : af;
        publishW(Wp, jb, w, (unsigned)t, af, Cnew, lane);
        Cuse = Cnew;
    }

    if (w == 0 && lane == 0) cshare = Cuse;   // C of the gen-127 publish

    // ---- tail (blocks jb==0 only): log_Z + gold score + output ----
    if (jb == 0) {
        const u64* R = xb + ((size_t)((Tn - 1) & 1) * Bn + b) * XSTR;
        const unsigned tg = (unsigned)(Tn - 1);
        const bool tact = (tid < NDATA);
        u64 qd = 0;
        bool ok = !tact;
        while (true) {
            if (!ok) { qd = ald64(R + tid); ok = ((u32)(qd >> 32) == tg); }
            if (__syncthreads_and(ok)) break;
        }
        float lsum = 0.f;
        if (tact) {
            unsigned pv = (unsigned)qd;
            int base = 4 * tid;               // p8 index j = 4*word + e
            lsum = (float)(pv & 0xff)         * eteos[base]
                 + (float)((pv >> 8)  & 0xff) * eteos[base + 1]
                 + (float)((pv >> 16) & 0xff) * eteos[base + 2]
                 + (float)((pv >> 24) & 0xff) * eteos[base + 3];
        }
        // gold-path score: thread tid<128 handles position tid
        float mk = 0.f, val = 0.f;
        if (tid < Tn) {
            mk = mask[b * Tn + tid];
            if (tid > 0) {
                int cur  = tags[b * Tn + tid];
                int prev = tags[b * Tn + tid - 1];
                val = (em[((size_t)b * Tn + tid) * S + cur]
                       + trans[prev * S + cur]) * mk;
            }
        }
        lsum = wave_sum_f(lsum);
        float vs = wave_sum_f(val);
        float ms = wave_sum_f(mk);
        if (lane == 0) { redv[w] = vs; redm[w] = ms; }
        if (lane == 1) redl[w] = lsum;
        __syncthreads();
        if (tid == 0) {
            float tot  = redl[0] + redl[1] + redl[2] + redl[3];
            float logz = cshare - KL127 + __logf(tot);
            float msum = redm[0] + redm[1] + redm[2] + redm[3];
            int last   = (int)(msum + 0.5f) - 1;
            int first  = tags[b * Tn];
            int lastt  = tags[b * Tn + last];
            float score = redv[0] + redv[1] + redv[2] + redv[3]
                        + trans[BOSs * S + first]
                        + em[((size_t)b * Tn) * S + first]
                        + trans[lastt * S + EOSs];
            atomicAdd(out, -(score - logz));
        }
    }
}

extern "C" void kernel_launch(void* const* d_in, const int* in_sizes, int n_in,
                              void* d_out, int out_size, void* d_ws, size_t ws_size,
                              hipStream_t stream) {
    const float* em    = (const float*)d_in[0];
    const int*   tags  = (const int*)d_in[1];
    const float* mask  = (const float*)d_in[2];
    const float* trans = (const float*)d_in[3];
    float* out = (float*)d_out;

    char* ws = (char*)d_ws;
    size_t off = 0;
    unsigned char* eswz = (unsigned char*)(ws + off);
    off += (size_t)ETOT;
    off = (off + 255) & ~(size_t)255;
    float* eteos = (float*)(ws + off); off += JPAD * sizeof(float);
    off = (off + 255) & ~(size_t)255;
    u64* xb = (u64*)(ws + off);        off += (size_t)2 * Bn * XSTR * sizeof(u64);

    // ws re-poisoned 0xAA pre-launch: stale tags (0xAAAAAAAA) never match t<128
    (void)hipMemsetAsync(out, 0, sizeof(float), stream);

    build_tabs<<<(ETOT + 255) / 256, 256, 0, stream>>>(trans, eswz, eteos);
    crf_fwd<<<dim3(JB, Bn), 256, 0, stream>>>(em, mask, trans, tags, eswz,
                                              eteos, xb, out);
}